// Round 2
// baseline (588.347 us; speedup 1.0000x reference)
//
#include <hip/hip_runtime.h>

namespace {

constexpr int L = 10000;   // links
constexpr int F = 8;       // input features
constexpr int H = 64;      // hidden size
constexpr int B = 32;      // batch

__device__ __forceinline__ float fsigmoid(float x) {
    return 1.0f / (1.0f + __expf(-x));
}
__device__ __forceinline__ float ftanh(float x) {
    return 2.0f / (1.0f + __expf(-2.0f * x)) - 1.0f;
}

__global__ __launch_bounds__(256, 4)
void gcrnn_cell(const float* __restrict__ hidden, const float* __restrict__ xin,
                const float* __restrict__ Wrh, const float* __restrict__ Brh,
                const float* __restrict__ Wri, const float* __restrict__ Bri,
                const float* __restrict__ Wuh, const float* __restrict__ Buh,
                const float* __restrict__ Wui, const float* __restrict__ Bui,
                const float* __restrict__ Wnh, const float* __restrict__ Bnh,
                const float* __restrict__ Wni, const float* __restrict__ Bni,
                float* __restrict__ out)
{
    // XCD-chunked bijective swizzle: 10000 % 8 == 0, each XCD gets a
    // contiguous run of 1250 links -> adjacent j share L2 lines on one XCD.
    const int bid = blockIdx.x;
    const int j = (bid & 7) * (L / 8) + (bid >> 3);

    // Only activations live in LDS (9 KB) -> occupancy is VGPR-bound, not LDS.
    __shared__ __align__(16) float sXh[H][B];    // [i][b] = hidden[b,i,j]
    __shared__ __align__(16) float sXi[F][B];    // [i][b] = xin[b,i,j]

    const int t = threadIdx.x;
    const int lane = t & 31;     // k0 = lane*2
    const int k0 = lane * 2;
    const int b0 = (t >> 5) * 4;

    // ---- stage activations (scattered 4B; adjacent-j blocks share L2 lines)
#pragma unroll
    for (int n = 0; n < (H * B) / 256; ++n) {
        const int idx = t + 256 * n;
        const int i = idx >> 5;
        const int b = idx & 31;
        sXh[i][b] = hidden[(size_t)(b * H + i) * L + j];
    }
    {
        const int i = t >> 5;
        const int b = t & 31;
        sXi[i][b] = xin[(size_t)(b * F + i) * L + j];
    }

    // ---- bias loads issued early: latency overlaps the GEMM loop
    float bR[2], bU[2], bNH[2], bNI[2];
#pragma unroll
    for (int kk = 0; kk < 2; ++kk) {
        const size_t o = (size_t)(k0 + kk) * L + j;
        bR[kk]  = Brh[o] + Bri[o];
        bU[kk]  = Buh[o] + Bui[o];
        bNH[kk] = Bnh[o];
        bNI[kk] = Bni[o];
    }

    // weight row pointers: per i the wave reads a coalesced 256B row per gate
    const float2* pR = (const float2*)(Wrh + (size_t)j * H * H) + lane;
    const float2* pU = (const float2*)(Wuh + (size_t)j * H * H) + lane;
    const float2* pN = (const float2*)(Wnh + (size_t)j * H * H) + lane;
    const float2* qR = (const float2*)(Wri + (size_t)j * F * H) + lane;
    const float2* qU = (const float2*)(Wui + (size_t)j * F * H) + lane;
    const float2* qN = (const float2*)(Wni + (size_t)j * F * H) + lane;

    __syncthreads();

    float accR[4][2] = {};
    float accU[4][2] = {};
    float accN[4][2] = {};   // new_hidden gemm (pre reset-multiply)
    float accNI[4][2] = {};  // new_input gemm

    // fused 3-gate hidden GEMM: x from LDS (broadcast), weights from global
    // (L1-resident coalesced streams); 24 FMAs per i per thread.
#pragma unroll 8
    for (int i = 0; i < H; ++i) {
        const float4 x = *(const float4*)&sXh[i][b0];
        const float2 wr = pR[i * (H / 2)];
        const float2 wu = pU[i * (H / 2)];
        const float2 wn = pN[i * (H / 2)];
        const float xs[4] = {x.x, x.y, x.z, x.w};
#pragma unroll
        for (int b = 0; b < 4; ++b) {
            accR[b][0] += xs[b] * wr.x;  accR[b][1] += xs[b] * wr.y;
            accU[b][0] += xs[b] * wu.x;  accU[b][1] += xs[b] * wu.y;
            accN[b][0] += xs[b] * wn.x;  accN[b][1] += xs[b] * wn.y;
        }
    }
#pragma unroll
    for (int i = 0; i < F; ++i) {
        const float4 x = *(const float4*)&sXi[i][b0];
        const float2 wr = qR[i * (H / 2)];
        const float2 wu = qU[i * (H / 2)];
        const float2 wn = qN[i * (H / 2)];
        const float xs[4] = {x.x, x.y, x.z, x.w};
#pragma unroll
        for (int b = 0; b < 4; ++b) {
            accR[b][0] += xs[b] * wr.x;  accR[b][1] += xs[b] * wr.y;
            accU[b][0] += xs[b] * wu.x;  accU[b][1] += xs[b] * wu.y;
            accNI[b][0] += xs[b] * wn.x; accNI[b][1] += xs[b] * wn.y;
        }
    }

#pragma unroll
    for (int b = 0; b < 4; ++b) {
#pragma unroll
        for (int kk = 0; kk < 2; ++kk) {
            const int k = k0 + kk;
            const float r = fsigmoid(accR[b][kk] + bR[kk]);
            const float u = fsigmoid(accU[b][kk] + bU[kk]);
            const float n = ftanh(r * (accN[b][kk] + bNH[kk]) + accNI[b][kk] + bNI[kk]);
            const float h = sXh[k][b0 + b];
            out[(size_t)((b0 + b) * H + k) * L + j] = (1.0f - u) * n + u * h;
        }
    }
}

} // namespace

extern "C" void kernel_launch(void* const* d_in, const int* in_sizes, int n_in,
                              void* d_out, int out_size, void* d_ws, size_t ws_size,
                              hipStream_t stream) {
    const float* hidden = (const float*)d_in[0];
    const float* xin    = (const float*)d_in[1];
    const float* Wrh    = (const float*)d_in[2];
    const float* Brh    = (const float*)d_in[3];
    const float* Wri    = (const float*)d_in[4];
    const float* Bri    = (const float*)d_in[5];
    const float* Wuh    = (const float*)d_in[6];
    const float* Buh    = (const float*)d_in[7];
    const float* Wui    = (const float*)d_in[8];
    const float* Bui    = (const float*)d_in[9];
    const float* Wnh    = (const float*)d_in[10];
    const float* Bnh    = (const float*)d_in[11];
    const float* Wni    = (const float*)d_in[12];
    const float* Bni    = (const float*)d_in[13];
    float* out = (float*)d_out;

    gcrnn_cell<<<L, 256, 0, stream>>>(hidden, xin,
                                      Wrh, Brh, Wri, Bri,
                                      Wuh, Buh, Wui, Bui,
                                      Wnh, Bnh, Wni, Bni,
                                      out);
}